// Round 20
// baseline (1408.604 us; speedup 1.0000x reference)
//
#include <hip/hip_runtime.h>
#include <math.h>

#define TT   1024
#define DM   768
#define NH   12
#define HD   64
#define FFD  2048
#define NE   8
#define SQ   512
#define NB   2
#define NL   4
#define NV   32000
#define REPS 1e-6f
#define QB   16

typedef float f32x4 __attribute__((ext_vector_type(4)));
typedef short s16x8 __attribute__((ext_vector_type(8)));

__device__ __forceinline__ float b2f(ushort u) {
  return __uint_as_float(((unsigned)u) << 16);
}
__device__ __forceinline__ ushort f2b(float f) {
  unsigned i = __float_as_uint(f);
  return (ushort)((i + 0x7FFFu + ((i >> 16) & 1u)) >> 16);
}
__device__ __forceinline__ ushort t2b(float f) {  // truncate: 1 VALU op
  return (ushort)(__float_as_uint(f) >> 16);
}

// ================= embed (+ zero all per-layer counts) =================
__global__ __launch_bounds__(256) void k_embed(const int* __restrict__ ids,
    const float* __restrict__ tok, const float* __restrict__ pos, float* __restrict__ x,
    int* __restrict__ counts4) {
  int t = blockIdx.x;
  if (t == 0 && threadIdx.x < NL * NE) counts4[threadIdx.x] = 0;
  int s = t % SQ; int id = ids[t];
  for (int d = threadIdx.x; d < DM; d += 256)
    x[t * DM + d] = tok[(size_t)id * DM + d] + pos[s * DM + d];
}

// ================= first-layer rmsnorm -> split =================
__global__ __launch_bounds__(256) void k_rmsnorm_sb(const float* __restrict__ x,
    const float* __restrict__ w, ushort* __restrict__ yh, ushort* __restrict__ yl) {
  __shared__ float red[256];
  int t = blockIdx.x, tid = threadIdx.x;
  float ss = 0.f;
  for (int d = tid; d < DM; d += 256) { float v = x[t * DM + d]; ss += v * v; }
  red[tid] = ss; __syncthreads();
  for (int s = 128; s > 0; s >>= 1) { if (tid < s) red[tid] += red[tid + s]; __syncthreads(); }
  float inv = 1.0f / sqrtf(red[0] / (float)DM + REPS);
  for (int d = tid; d < DM; d += 256) {
    float v = w[d] * x[t * DM + d] * inv;
    ushort h = f2b(v);
    yh[t * DM + d] = h;
    yl[t * DM + d] = f2b(v - b2f(h));
  }
}

// ================= fused MoE rmsnorm + router =================
__global__ __launch_bounds__(256) void k_rmsnorm_rt(const float* __restrict__ x,
    const float* __restrict__ nw, const float* __restrict__ rw,
    ushort* __restrict__ yh, ushort* __restrict__ yl,
    int* __restrict__ topi, float* __restrict__ topw,
    int* __restrict__ posb, int* __restrict__ slot, int* __restrict__ counts) {
  __shared__ float red[256];
  __shared__ float rw4[4][NE];
  int t = blockIdx.x, tid = threadIdx.x;
  float xs[3];
  float ss = 0.f;
#pragma unroll
  for (int i = 0; i < 3; ++i) {
    float v = x[t * DM + tid + 256 * i];
    xs[i] = v; ss += v * v;
  }
  red[tid] = ss; __syncthreads();
  for (int s = 128; s > 0; s >>= 1) { if (tid < s) red[tid] += red[tid + s]; __syncthreads(); }
  float inv = 1.0f / sqrtf(red[0] / (float)DM + REPS);
  float acc[NE] = {};
#pragma unroll
  for (int i = 0; i < 3; ++i) {
    int d = tid + 256 * i;
    float v = nw[d] * xs[i] * inv;
    ushort h = f2b(v);
    yh[t * DM + d] = h;
    yl[t * DM + d] = f2b(v - b2f(h));
    const float* r = &rw[d * NE];
#pragma unroll
    for (int e = 0; e < NE; ++e) acc[e] += v * r[e];
  }
#pragma unroll
  for (int off = 32; off > 0; off >>= 1)
#pragma unroll
    for (int e = 0; e < NE; ++e) acc[e] += __shfl_down(acc[e], off, 64);
  int wv = tid >> 6, ln = tid & 63;
  if (ln == 0)
#pragma unroll
    for (int e = 0; e < NE; ++e) rw4[wv][e] = acc[e];
  __syncthreads();
  if (tid == 0) {
    float lg[NE];
#pragma unroll
    for (int e = 0; e < NE; ++e) lg[e] = rw4[0][e] + rw4[1][e] + rw4[2][e] + rw4[3][e];
    int i0 = 0;
    for (int e = 1; e < NE; ++e) if (lg[e] > lg[i0]) i0 = e;
    int i1 = (i0 == 0) ? 1 : 0;
    for (int e = 0; e < NE; ++e) if (e != i0 && lg[e] > lg[i1]) i1 = e;
    float e1 = __expf(lg[i1] - lg[i0]);
    float w0 = 1.f / (1.f + e1), w1 = e1 / (1.f + e1);
    int p0 = atomicAdd(&counts[i0], 1);
    int p1 = atomicAdd(&counts[i1], 1);
    topi[2 * t] = i0; topi[2 * t + 1] = i1;
    topw[2 * t] = w0; topw[2 * t + 1] = w1;
    posb[2 * t] = p0; posb[2 * t + 1] = p1;
    slot[i0 * TT + p0] = t; slot[i1 * TT + p1] = t;
  }
}

// ================= fused combine + next norm =================
template<int FINAL>
__global__ __launch_bounds__(256) void k_combine_norm(const float* __restrict__ eo,
    const int* __restrict__ topi, const float* __restrict__ topw,
    const int* __restrict__ posb, const int* __restrict__ counts,
    float* __restrict__ x, const float* __restrict__ w,
    ushort* __restrict__ yh, ushort* __restrict__ yl) {
  __shared__ float red[256];
  int t = blockIdx.x, tid = threadIdx.x;
  int pre[NE]; int a = 0;
#pragma unroll
  for (int e = 0; e < NE; ++e) { pre[e] = a; a += counts[e]; }
  int r0 = pre[topi[2 * t]] + posb[2 * t];
  int r1 = pre[topi[2 * t + 1]] + posb[2 * t + 1];
  float w0 = topw[2 * t], w1 = topw[2 * t + 1];
  float nv[3];
  float ss = 0.f;
#pragma unroll
  for (int i = 0; i < 3; ++i) {
    int d = tid + 256 * i;
    float v = x[t * DM + d] + w0 * eo[(size_t)r0 * DM + d] + w1 * eo[(size_t)r1 * DM + d];
    x[t * DM + d] = v;
    nv[i] = v; ss += v * v;
  }
  red[tid] = ss; __syncthreads();
  for (int s = 128; s > 0; s >>= 1) { if (tid < s) red[tid] += red[tid + s]; __syncthreads(); }
  float inv = 1.0f / sqrtf(red[0] / (float)DM + REPS);
#pragma unroll
  for (int i = 0; i < 3; ++i) {
    int d = tid + 256 * i;
    float u = w[d] * nv[i] * inv;
    if (FINAL) {
      yh[t * DM + d] = f2b(u);
    } else {
      ushort h = f2b(u);
      yh[t * DM + d] = h;
      yl[t * DM + d] = f2b(u - b2f(h));
    }
  }
}

// ================= tiled fp32 attention, split-output epilogue (r15-verified) =================
__global__ __launch_bounds__(256) void k_attn2(const float* __restrict__ qkv,
    ushort* __restrict__ aoh, ushort* __restrict__ aol) {
  __shared__ float Qs[QB][64];
  __shared__ float KVs[128][68];
  __shared__ float sc[QB][516];
  __shared__ float red[256];
  __shared__ float mrow[QB], invr[QB];
  int qt = blockIdx.x, h = blockIdx.y, b = blockIdx.z;
  int tid = threadIdx.x;
  int q0 = qt * QB;
  const float* base = qkv + (size_t)(b * SQ) * (3 * DM);
  {
    int qi = tid >> 4, d4 = (tid & 15) * 4;
    *(float4*)&Qs[qi][d4] = *(const float4*)&base[(size_t)(q0 + qi) * (3 * DM) + h * HD + d4];
  }
  for (int kt = 0; kt < 4; ++kt) {
    __syncthreads();
    {
      int kk = tid >> 4, d4 = (tid & 15) * 4;
#pragma unroll
      for (int i = 0; i < 8; ++i)
        *(float4*)&KVs[kk + 16 * i][d4] =
            *(const float4*)&base[(size_t)(kt * 128 + kk + 16 * i) * (3 * DM) + DM + h * HD + d4];
    }
    __syncthreads();
    int q2 = tid >> 5, k4 = tid & 31;
    float a0[4] = {}, a1[4] = {};
#pragma unroll
    for (int i = 0; i < 16; ++i) {
      float4 qa = *(float4*)&Qs[2 * q2][4 * i];
      float4 qb = *(float4*)&Qs[2 * q2 + 1][4 * i];
#pragma unroll
      for (int j = 0; j < 4; ++j) {
        float4 kv = *(float4*)&KVs[k4 + 32 * j][4 * i];
        a0[j] += qa.x * kv.x + qa.y * kv.y + qa.z * kv.z + qa.w * kv.w;
        a1[j] += qb.x * kv.x + qb.y * kv.y + qb.z * kv.z + qb.w * kv.w;
      }
    }
#pragma unroll
    for (int j = 0; j < 4; ++j) {
      sc[2 * q2][kt * 128 + 32 * j + k4] = a0[j] * 0.125f;
      sc[2 * q2 + 1][kt * 128 + 32 * j + k4] = a1[j] * 0.125f;
    }
  }
  __syncthreads();
  int row = tid & 15, seg = tid >> 4;
  float m = -1e30f;
  for (int i = 0; i < 32; ++i) m = fmaxf(m, sc[row][seg + 16 * i]);
  red[tid] = m; __syncthreads();
  if (tid < QB) {
    float mm = red[tid];
#pragma unroll
    for (int j = 1; j < 16; ++j) mm = fmaxf(mm, red[tid + 16 * j]);
    mrow[tid] = mm;
  }
  __syncthreads();
  m = mrow[row];
  float s = 0.f;
  for (int i = 0; i < 32; ++i) {
    int c = seg + 16 * i;
    float e = expf(sc[row][c] - m);
    sc[row][c] = e; s += e;
  }
  red[tid] = s; __syncthreads();
  if (tid < QB) {
    float ss = red[tid];
#pragma unroll
    for (int j = 1; j < 16; ++j) ss += red[tid + 16 * j];
    invr[tid] = 1.0f / ss;
  }
  float4 o = {0.f, 0.f, 0.f, 0.f};
  int q = tid >> 4, d4 = (tid & 15) * 4;
  for (int vt = 0; vt < 4; ++vt) {
    __syncthreads();
    {
      int kk = tid >> 4, dd = (tid & 15) * 4;
#pragma unroll
      for (int i = 0; i < 8; ++i)
        *(float4*)&KVs[kk + 16 * i][dd] =
            *(const float4*)&base[(size_t)(vt * 128 + kk + 16 * i) * (3 * DM) + 2 * DM + h * HD + dd];
    }
    __syncthreads();
    for (int kk = 0; kk < 128; ++kk) {
      float w = sc[q][vt * 128 + kk];
      float4 v = *(float4*)&KVs[kk][d4];
      o.x += w * v.x; o.y += w * v.y; o.z += w * v.z; o.w += w * v.w;
    }
  }
  float iv = invr[q];
  size_t ob = (size_t)(b * SQ + q0 + q) * DM + h * HD + d4;
  float ov[4] = {o.x * iv, o.y * iv, o.z * iv, o.w * iv};
#pragma unroll
  for (int j = 0; j < 4; ++j) {
    ushort hh = f2b(ov[j]);
    aoh[ob + j] = hh;
    aol[ob + j] = f2b(ov[j] - b2f(hh));
  }
}

// ================= pipelined GEMM (r17-verified core; trunc-split staging) =================
#define EPI_RES  1
#define EPI_F32  2
#define EPI_GU   3
#define EPI_DOWN 4
#define MODE_B   0
#define MODE_QKV 1
#define MODE_GU  2

template<int BM, int BN, int MODE, int EPI, int RM, int NBX, int PREC, int DEC>
__global__ __launch_bounds__(256) void k_gmm2(
    const ushort* __restrict__ Ah, const ushort* __restrict__ Al,
    const float* __restrict__ B0, const float* __restrict__ B1, const float* __restrict__ B2,
    long long bstride, ushort* __restrict__ Ch, ushort* __restrict__ Cl,
    float* __restrict__ Cf,
    int M, int K, int ldb, int ldc,
    const int* __restrict__ slot, const int* __restrict__ counts) {
  constexpr int NEg  = (RM == 0) ? 1 : NE;
  constexpr int P    = NBX * NEg;
  constexpr int Ppad = ((P + 7) / 8) * 8;
  constexpr int MB   = TT / BM;
  int id = blockIdx.x;
  int m, pp;
  if (DEC == 0) { m = id / Ppad; pp = id % Ppad; }
  else {  // DEC==2: XCD-grouped panels
    int xcd = id & 7, j = id >> 3;
    m = j % MB;
    pp = (j / MB) * 8 + xcd;
  }
  if (pp >= P) return;
  int e = pp / NBX;
  int x = pp % NBX;

  int cnt = (RM == 0) ? M : counts[e];
  int m0 = m * BM;
  if (m0 >= cnt) return;
  int n0 = x * BN;
  int off = 0;
  if (RM != 0) {
#pragma unroll
    for (int i = 0; i < NE; ++i) if (i < e) off += counts[i];
  }

  constexpr int WM = (BM == 128) ? 64 : ((BN == 128) ? 64 : 32);
  constexpr int WN = (BM == 128) ? 64 : 32;
  constexpr int MI = WM / 16, NI = WN / 16;

  __shared__ __align__(16) ushort Ahs[BM * 40];
  __shared__ __align__(16) ushort Als[(PREC == 2) ? BM * 40 : 16];
  __shared__ __align__(16) ushort Bhs[BN * 40];
  __shared__ __align__(16) ushort Bls[(PREC == 2) ? BN * 40 : 16];

  int tid = threadIdx.x;
  int wave = tid >> 6, lane = tid & 63;
  int wr, wc;
  if (BM == 128)      { wr = wave >> 1; wc = wave & 1; }
  else if (BN == 128) { wr = 0;         wc = wave;     }
  else                { wr = wave >> 1; wc = wave & 1; }
  int moff;
  if (BM == 64 && BN == 128) moff = 0; else moff = wr * ((BM == 128) ? 64 : 32);
  int noff = wc * WN;

  int arA = tid >> 2, kcA = tid & 3;
  int ar1 = tid >> 2, ar2 = ar1 + 64;
  size_t aoff1 = 0, aoff2 = 0;
  if (BM == 64) {
    int rowi;
    if (RM == 0)      rowi = m0 + arA;
    else if (RM == 1) rowi = slot[e * TT + min(m0 + arA, cnt - 1)];
    else              rowi = off + min(m0 + arA, cnt - 1);
    aoff1 = (size_t)rowi * K;
  } else {
    if (RM == 0) {
      aoff1 = (size_t)(m0 + ar1) * K;
      aoff2 = (size_t)(m0 + ar2) * K;
    } else if (RM == 1) {
      aoff1 = (size_t)slot[e * TT + min(m0 + ar1, cnt - 1)] * K;
      aoff2 = (size_t)slot[e * TT + min(m0 + ar2, cnt - 1)] * K;
    } else {
      aoff1 = (size_t)(off + min(m0 + ar1, cnt - 1)) * K;
      aoff2 = (size_t)(off + min(m0 + ar2, cnt - 1)) * K;
    }
  }

  int rB = tid & 63, ko = tid >> 6;
  auto bcol = [&](int r) -> const float* {
    if (MODE == MODE_QKV) {
      int mat = x / (NBX / 3);
      const float* Bm = (mat == 0) ? B0 : ((mat == 1) ? B1 : B2);
      return Bm + (x % (NBX / 3)) * BN + r;
    } else if (MODE == MODE_GU) {
      const float* Bg = B0 + (size_t)e * bstride;
      const float* Bu = B1 + (size_t)e * bstride;
      return ((((r) >> 4) & 1) ? Bu : Bg) + x * (BN / 2) + ((((r) >> 5) << 4) | ((r) & 15));
    }
    return B0 + (size_t)e * bstride + n0 + r;
  };
  const float* bs0 = bcol(rB);
  const float* bs1 = (BN == 128) ? bcol(rB + 64) : nullptr;

  s16x8 rah1, rah2, ral1, ral2;
  float vb0[8], vb1[8];

  auto loadA = [&](int kk) {
    if (BM == 64) {
      rah1 = *(const s16x8*)(Ah + aoff1 + kk + kcA * 8);
      if (PREC == 2) ral1 = *(const s16x8*)(Al + aoff1 + kk + kcA * 8);
    } else {
      rah1 = *(const s16x8*)(Ah + aoff1 + kk + kcA * 8);
      rah2 = *(const s16x8*)(Ah + aoff2 + kk + kcA * 8);
      if (PREC == 2) {
        ral1 = *(const s16x8*)(Al + aoff1 + kk + kcA * 8);
        ral2 = *(const s16x8*)(Al + aoff2 + kk + kcA * 8);
      }
    }
  };
  auto loadB = [&](int kk) {
#pragma unroll
    for (int i = 0; i < 8; ++i)
      vb0[i] = bs0[(size_t)(kk + ko * 8 + i) * ldb];
    if (BN == 128) {
#pragma unroll
      for (int i = 0; i < 8; ++i)
        vb1[i] = bs1[(size_t)(kk + ko * 8 + i) * ldb];
    }
  };
  auto storeLDS = [&]() {
    if (BM == 64) {
      *(s16x8*)&Ahs[arA * 40 + kcA * 8] = rah1;
      if (PREC == 2) *(s16x8*)&Als[arA * 40 + kcA * 8] = ral1;
    } else {
      *(s16x8*)&Ahs[ar1 * 40 + kcA * 8] = rah1;
      *(s16x8*)&Ahs[ar2 * 40 + kcA * 8] = rah2;
      if (PREC == 2) {
        *(s16x8*)&Als[ar1 * 40 + kcA * 8] = ral1;
        *(s16x8*)&Als[ar2 * 40 + kcA * 8] = ral2;
      }
    }
    s16x8 h0, l0;
#pragma unroll
    for (int i = 0; i < 8; ++i) {
      ushort h = t2b(vb0[i]);
      h0[i] = (short)h;
      if (PREC == 2) l0[i] = (short)t2b(vb0[i] - b2f(h));
    }
    *(s16x8*)&Bhs[rB * 40 + ko * 8] = h0;
    if (PREC == 2) *(s16x8*)&Bls[rB * 40 + ko * 8] = l0;
    if (BN == 128) {
      s16x8 h1, l1;
#pragma unroll
      for (int i = 0; i < 8; ++i) {
        ushort h = t2b(vb1[i]);
        h1[i] = (short)h;
        if (PREC == 2) l1[i] = (short)t2b(vb1[i] - b2f(h));
      }
      *(s16x8*)&Bhs[(rB + 64) * 40 + ko * 8] = h1;
      if (PREC == 2) *(s16x8*)&Bls[(rB + 64) * 40 + ko * 8] = l1;
    }
  };

  f32x4 zr = {0.f, 0.f, 0.f, 0.f};
  f32x4 acc[MI][NI];
#pragma unroll
  for (int i = 0; i < MI; ++i)
#pragma unroll
    for (int j = 0; j < NI; ++j) acc[i][j] = zr;

  int rl = lane & 15, g = lane >> 4;
  loadA(0); loadB(0);
  for (int k0 = 0; k0 < K; k0 += 32) {
    __syncthreads();
    storeLDS();
    __syncthreads();
    if (k0 + 32 < K) { loadA(k0 + 32); loadB(k0 + 32); }
#pragma unroll
    for (int mi = 0; mi < MI; ++mi) {
      int ra = (moff + mi * 16 + rl) * 40 + g * 8;
      s16x8 avh = *(const s16x8*)&Ahs[ra];
      s16x8 avl;
      if (PREC == 2) avl = *(const s16x8*)&Als[ra];
#pragma unroll
      for (int ni = 0; ni < NI; ++ni) {
        int rb = (noff + ni * 16 + rl) * 40 + g * 8;
        s16x8 bvh = *(const s16x8*)&Bhs[rb];
        f32x4 a = acc[mi][ni];
        if (PREC == 2) {
          s16x8 bvl = *(const s16x8*)&Bls[rb];
          a = __builtin_amdgcn_mfma_f32_16x16x32_bf16(avl, bvh, a, 0, 0, 0);
          a = __builtin_amdgcn_mfma_f32_16x16x32_bf16(avh, bvl, a, 0, 0, 0);
        }
        a = __builtin_amdgcn_mfma_f32_16x16x32_bf16(avh, bvh, a, 0, 0, 0);
        acc[mi][ni] = a;
      }
    }
  }

  int rg4 = (lane >> 4) * 4;
#pragma unroll
  for (int mi = 0; mi < MI; ++mi) {
#pragma unroll
    for (int rg = 0; rg < 4; ++rg) {
      int rloc = m0 + moff + mi * 16 + rg4 + rg;
      if ((EPI == EPI_GU || EPI == EPI_DOWN) && rloc >= cnt) continue;
      if (EPI == EPI_GU) {
        float gv = acc[mi][0][rg], uv = acc[mi][1][rg];
        float hv = gv / (1.f + __expf(-gv)) * uv;
        int fq = (n0 + noff) >> 5;
        size_t ix = (size_t)(off + rloc) * ldc + fq * 16 + rl;
        ushort h = t2b(hv);
        Ch[ix] = h;
        if (PREC == 2) Cl[ix] = t2b(hv - b2f(h));
      } else if (EPI == EPI_RES) {
#pragma unroll
        for (int ni = 0; ni < NI; ++ni) {
          size_t ix = (size_t)rloc * ldc + n0 + noff + ni * 16 + rl;
          Cf[ix] += acc[mi][ni][rg];
        }
      } else if (EPI == EPI_F32) {
#pragma unroll
        for (int ni = 0; ni < NI; ++ni)
          Cf[(size_t)rloc * ldc + n0 + noff + ni * 16 + rl] = acc[mi][ni][rg];
      } else {  // EPI_DOWN
#pragma unroll
        for (int ni = 0; ni < NI; ++ni)
          Cf[(size_t)(off + rloc) * ldc + n0 + noff + ni * 16 + rl] = acc[mi][ni][rg];
      }
    }
  }
}

extern "C" void kernel_launch(void* const* d_in, const int* in_sizes, int n_in,
                              void* d_out, int out_size, void* d_ws, size_t ws_size,
                              hipStream_t stream) {
  (void)in_sizes; (void)n_in; (void)out_size; (void)ws_size;
  const int*   ids = (const int*)d_in[0];
  const float* tok = (const float*)d_in[1];
  const float* pos = (const float*)d_in[2];
  const float* wq  = (const float*)d_in[3];
  const float* wk  = (const float*)d_in[4];
  const float* wv  = (const float*)d_in[5];
  const float* wo  = (const float*)d_in[6];
  const float* n1w = (const float*)d_in[7];
  const float* n2w = (const float*)d_in[8];
  const float* rw  = (const float*)d_in[9];
  const float* gw  = (const float*)d_in[10];
  const float* uw  = (const float*)d_in[11];
  const float* dw  = (const float*)d_in[12];
  const float* fnw = (const float*)d_in[13];
  const float* lmw = (const float*)d_in[14];
  float* out = (float*)d_out;

  char* p = (char*)d_ws;
  auto alloc = [&](size_t bytes) { char* r = p; p += (bytes + 255) & ~(size_t)255; return r; };
  float*  x    = (float*)alloc((size_t)TT * DM * 4);
  ushort* xh   = (ushort*)alloc((size_t)TT * DM * 2);
  ushort* xl   = (ushort*)alloc((size_t)TT * DM * 2);
  float*  qkv  = (float*)alloc((size_t)TT * 3 * DM * 4);
  ushort* aoh  = (ushort*)alloc((size_t)TT * DM * 2);
  ushort* aol  = (ushort*)alloc((size_t)TT * DM * 2);
  ushort* Hh   = (ushort*)alloc((size_t)2 * TT * FFD * 2);
  ushort* Hl   = (ushort*)alloc((size_t)2 * TT * FFD * 2);
  float*  eo   = (float*)alloc((size_t)2 * TT * DM * 4);
  float*  topw = (float*)alloc((size_t)2 * TT * 4);
  int* topi    = (int*)alloc((size_t)2 * TT * 4);
  int* posb    = (int*)alloc((size_t)2 * TT * 4);
  int* slot    = (int*)alloc((size_t)NE * TT * 4);
  int* counts4 = (int*)alloc(256);
  ushort* xnb  = (ushort*)alloc((size_t)TT * DM * 2);

  k_embed<<<TT, 256, 0, stream>>>(ids, tok, pos, x, counts4);
  k_rmsnorm_sb<<<TT, 256, 0, stream>>>(x, n1w, xh, xl);
  for (int l = 0; l < NL; ++l) {
    int* counts = counts4 + NE * l;
    // attention: QKV now BN=128 (GU-verified geometry), NBX=18 -> Ppad=24
    k_gmm2<64, 128, MODE_QKV, EPI_F32, 0, 18, 2, 0><<<16 * 24, 256, 0, stream>>>(
        xh, xl, wq + (size_t)l * DM * DM, wk + (size_t)l * DM * DM, wv + (size_t)l * DM * DM,
        0, nullptr, nullptr, qkv, TT, DM, DM, 3 * DM, nullptr, nullptr);
    k_attn2<<<dim3(SQ / QB, NH, NB), 256, 0, stream>>>(qkv, aoh, aol);
    // O-proj: BN=128, NBX=6 -> Ppad=8
    k_gmm2<64, 128, MODE_B, EPI_RES, 0, 6, 2, 0><<<16 * 8, 256, 0, stream>>>(
        aoh, aol, wo + (size_t)l * DM * DM, nullptr, nullptr,
        0, nullptr, nullptr, x, TT, DM, DM, DM, nullptr, nullptr);

    // MoE: fused norm+router, then expert GEMMs
    k_rmsnorm_rt<<<TT, 256, 0, stream>>>(x, n2w + l * DM, rw + (size_t)l * DM * NE,
                                         xh, xl, topi, topw, posb, slot, counts);
    if (l < NL - 1) {
      k_gmm2<64, 128, MODE_GU, EPI_GU, 1, 32, 2, 0><<<16 * 256, 256, 0, stream>>>(
          xh, xl, gw + (size_t)l * NE * DM * FFD, uw + (size_t)l * NE * DM * FFD, nullptr,
          (long long)DM * FFD, Hh, Hl, nullptr, TT, DM, FFD, FFD, slot, counts);
      // down: BN=128, NBX=6, P=48
      k_gmm2<64, 128, MODE_B, EPI_DOWN, 2, 6, 2, 0><<<16 * 48, 256, 0, stream>>>(
          Hh, Hl, dw + (size_t)l * NE * FFD * DM, nullptr, nullptr,
          (long long)FFD * DM, nullptr, nullptr, eo, TT, FFD, DM, DM, nullptr, counts);
      k_combine_norm<0><<<TT, 256, 0, stream>>>(eo, topi, topw, posb, counts,
                                                x, n1w + (size_t)(l + 1) * DM, xh, xl);
    } else {
      k_gmm2<64, 128, MODE_GU, EPI_GU, 1, 32, 1, 0><<<16 * 256, 256, 0, stream>>>(
          xh, nullptr, gw + (size_t)l * NE * DM * FFD, uw + (size_t)l * NE * DM * FFD, nullptr,
          (long long)DM * FFD, Hh, nullptr, nullptr, TT, DM, FFD, FFD, slot, counts);
      k_gmm2<64, 128, MODE_B, EPI_DOWN, 2, 6, 1, 0><<<16 * 48, 256, 0, stream>>>(
          Hh, nullptr, dw + (size_t)l * NE * FFD * DM, nullptr, nullptr,
          (long long)FFD * DM, nullptr, nullptr, eo, TT, FFD, DM, DM, nullptr, counts);
      k_combine_norm<1><<<TT, 256, 0, stream>>>(eo, topi, topw, posb, counts,
                                                x, fnw, xnb, nullptr);
    }
  }

  // LM head: single launch, XCD-grouped panel decode
  k_gmm2<64, 128, MODE_B, EPI_F32, 0, 250, 1, 2><<<16 * 256, 256, 0, stream>>>(
      xnb, nullptr, lmw, nullptr, nullptr,
      0, nullptr, nullptr, out, TT, DM, NV, NV, nullptr, nullptr);
}

// Round 21
// 1338.409 us; speedup vs baseline: 1.0524x; 1.0524x over previous
//
#include <hip/hip_runtime.h>
#include <math.h>

#define TT   1024
#define DM   768
#define NH   12
#define HD   64
#define FFD  2048
#define NE   8
#define SQ   512
#define NB   2
#define NL   4
#define NV   32000
#define REPS 1e-6f
#define QB   16

typedef float f32x4 __attribute__((ext_vector_type(4)));
typedef short s16x8 __attribute__((ext_vector_type(8)));

__device__ __forceinline__ float b2f(ushort u) {
  return __uint_as_float(((unsigned)u) << 16);
}
__device__ __forceinline__ ushort f2b(float f) {
  unsigned i = __float_as_uint(f);
  return (ushort)((i + 0x7FFFu + ((i >> 16) & 1u)) >> 16);
}
__device__ __forceinline__ ushort t2b(float f) {  // truncate: 1 VALU op
  return (ushort)(__float_as_uint(f) >> 16);
}

// ================= embed (+ zero all per-layer counts) =================
__global__ __launch_bounds__(256) void k_embed(const int* __restrict__ ids,
    const float* __restrict__ tok, const float* __restrict__ pos, float* __restrict__ x,
    int* __restrict__ counts4) {
  int t = blockIdx.x;
  if (t == 0 && threadIdx.x < NL * NE) counts4[threadIdx.x] = 0;
  int s = t % SQ; int id = ids[t];
  for (int d = threadIdx.x; d < DM; d += 256)
    x[t * DM + d] = tok[(size_t)id * DM + d] + pos[s * DM + d];
}

// ================= first-layer rmsnorm -> split =================
__global__ __launch_bounds__(256) void k_rmsnorm_sb(const float* __restrict__ x,
    const float* __restrict__ w, ushort* __restrict__ yh, ushort* __restrict__ yl) {
  __shared__ float red[256];
  int t = blockIdx.x, tid = threadIdx.x;
  float ss = 0.f;
  for (int d = tid; d < DM; d += 256) { float v = x[t * DM + d]; ss += v * v; }
  red[tid] = ss; __syncthreads();
  for (int s = 128; s > 0; s >>= 1) { if (tid < s) red[tid] += red[tid + s]; __syncthreads(); }
  float inv = 1.0f / sqrtf(red[0] / (float)DM + REPS);
  for (int d = tid; d < DM; d += 256) {
    float v = w[d] * x[t * DM + d] * inv;
    ushort h = f2b(v);
    yh[t * DM + d] = h;
    yl[t * DM + d] = f2b(v - b2f(h));
  }
}

// ================= fused MoE rmsnorm + router =================
__global__ __launch_bounds__(256) void k_rmsnorm_rt(const float* __restrict__ x,
    const float* __restrict__ nw, const float* __restrict__ rw,
    ushort* __restrict__ yh, ushort* __restrict__ yl,
    int* __restrict__ topi, float* __restrict__ topw,
    int* __restrict__ posb, int* __restrict__ slot, int* __restrict__ counts) {
  __shared__ float red[256];
  __shared__ float rw4[4][NE];
  int t = blockIdx.x, tid = threadIdx.x;
  float xs[3];
  float ss = 0.f;
#pragma unroll
  for (int i = 0; i < 3; ++i) {
    float v = x[t * DM + tid + 256 * i];
    xs[i] = v; ss += v * v;
  }
  red[tid] = ss; __syncthreads();
  for (int s = 128; s > 0; s >>= 1) { if (tid < s) red[tid] += red[tid + s]; __syncthreads(); }
  float inv = 1.0f / sqrtf(red[0] / (float)DM + REPS);
  float acc[NE] = {};
#pragma unroll
  for (int i = 0; i < 3; ++i) {
    int d = tid + 256 * i;
    float v = nw[d] * xs[i] * inv;
    ushort h = f2b(v);
    yh[t * DM + d] = h;
    yl[t * DM + d] = f2b(v - b2f(h));
    const float* r = &rw[d * NE];
#pragma unroll
    for (int e = 0; e < NE; ++e) acc[e] += v * r[e];
  }
#pragma unroll
  for (int off = 32; off > 0; off >>= 1)
#pragma unroll
    for (int e = 0; e < NE; ++e) acc[e] += __shfl_down(acc[e], off, 64);
  int wv = tid >> 6, ln = tid & 63;
  if (ln == 0)
#pragma unroll
    for (int e = 0; e < NE; ++e) rw4[wv][e] = acc[e];
  __syncthreads();
  if (tid == 0) {
    float lg[NE];
#pragma unroll
    for (int e = 0; e < NE; ++e) lg[e] = rw4[0][e] + rw4[1][e] + rw4[2][e] + rw4[3][e];
    int i0 = 0;
    for (int e = 1; e < NE; ++e) if (lg[e] > lg[i0]) i0 = e;
    int i1 = (i0 == 0) ? 1 : 0;
    for (int e = 0; e < NE; ++e) if (e != i0 && lg[e] > lg[i1]) i1 = e;
    float e1 = __expf(lg[i1] - lg[i0]);
    float w0 = 1.f / (1.f + e1), w1 = e1 / (1.f + e1);
    int p0 = atomicAdd(&counts[i0], 1);
    int p1 = atomicAdd(&counts[i1], 1);
    topi[2 * t] = i0; topi[2 * t + 1] = i1;
    topw[2 * t] = w0; topw[2 * t + 1] = w1;
    posb[2 * t] = p0; posb[2 * t + 1] = p1;
    slot[i0 * TT + p0] = t; slot[i1 * TT + p1] = t;
  }
}

// ================= fused combine + next norm =================
template<int FINAL>
__global__ __launch_bounds__(256) void k_combine_norm(const float* __restrict__ eo,
    const int* __restrict__ topi, const float* __restrict__ topw,
    const int* __restrict__ posb, const int* __restrict__ counts,
    float* __restrict__ x, const float* __restrict__ w,
    ushort* __restrict__ yh, ushort* __restrict__ yl) {
  __shared__ float red[256];
  int t = blockIdx.x, tid = threadIdx.x;
  int pre[NE]; int a = 0;
#pragma unroll
  for (int e = 0; e < NE; ++e) { pre[e] = a; a += counts[e]; }
  int r0 = pre[topi[2 * t]] + posb[2 * t];
  int r1 = pre[topi[2 * t + 1]] + posb[2 * t + 1];
  float w0 = topw[2 * t], w1 = topw[2 * t + 1];
  float nv[3];
  float ss = 0.f;
#pragma unroll
  for (int i = 0; i < 3; ++i) {
    int d = tid + 256 * i;
    float v = x[t * DM + d] + w0 * eo[(size_t)r0 * DM + d] + w1 * eo[(size_t)r1 * DM + d];
    x[t * DM + d] = v;
    nv[i] = v; ss += v * v;
  }
  red[tid] = ss; __syncthreads();
  for (int s = 128; s > 0; s >>= 1) { if (tid < s) red[tid] += red[tid + s]; __syncthreads(); }
  float inv = 1.0f / sqrtf(red[0] / (float)DM + REPS);
#pragma unroll
  for (int i = 0; i < 3; ++i) {
    int d = tid + 256 * i;
    float u = w[d] * nv[i] * inv;
    if (FINAL) {
      yh[t * DM + d] = f2b(u);
    } else {
      ushort h = f2b(u);
      yh[t * DM + d] = h;
      yl[t * DM + d] = f2b(u - b2f(h));
    }
  }
}

// ================= tiled fp32 attention, split-output epilogue (r15-verified) =================
__global__ __launch_bounds__(256) void k_attn2(const float* __restrict__ qkv,
    ushort* __restrict__ aoh, ushort* __restrict__ aol) {
  __shared__ float Qs[QB][64];
  __shared__ float KVs[128][68];
  __shared__ float sc[QB][516];
  __shared__ float red[256];
  __shared__ float mrow[QB], invr[QB];
  int qt = blockIdx.x, h = blockIdx.y, b = blockIdx.z;
  int tid = threadIdx.x;
  int q0 = qt * QB;
  const float* base = qkv + (size_t)(b * SQ) * (3 * DM);
  {
    int qi = tid >> 4, d4 = (tid & 15) * 4;
    *(float4*)&Qs[qi][d4] = *(const float4*)&base[(size_t)(q0 + qi) * (3 * DM) + h * HD + d4];
  }
  for (int kt = 0; kt < 4; ++kt) {
    __syncthreads();
    {
      int kk = tid >> 4, d4 = (tid & 15) * 4;
#pragma unroll
      for (int i = 0; i < 8; ++i)
        *(float4*)&KVs[kk + 16 * i][d4] =
            *(const float4*)&base[(size_t)(kt * 128 + kk + 16 * i) * (3 * DM) + DM + h * HD + d4];
    }
    __syncthreads();
    int q2 = tid >> 5, k4 = tid & 31;
    float a0[4] = {}, a1[4] = {};
#pragma unroll
    for (int i = 0; i < 16; ++i) {
      float4 qa = *(float4*)&Qs[2 * q2][4 * i];
      float4 qb = *(float4*)&Qs[2 * q2 + 1][4 * i];
#pragma unroll
      for (int j = 0; j < 4; ++j) {
        float4 kv = *(float4*)&KVs[k4 + 32 * j][4 * i];
        a0[j] += qa.x * kv.x + qa.y * kv.y + qa.z * kv.z + qa.w * kv.w;
        a1[j] += qb.x * kv.x + qb.y * kv.y + qb.z * kv.z + qb.w * kv.w;
      }
    }
#pragma unroll
    for (int j = 0; j < 4; ++j) {
      sc[2 * q2][kt * 128 + 32 * j + k4] = a0[j] * 0.125f;
      sc[2 * q2 + 1][kt * 128 + 32 * j + k4] = a1[j] * 0.125f;
    }
  }
  __syncthreads();
  int row = tid & 15, seg = tid >> 4;
  float m = -1e30f;
  for (int i = 0; i < 32; ++i) m = fmaxf(m, sc[row][seg + 16 * i]);
  red[tid] = m; __syncthreads();
  if (tid < QB) {
    float mm = red[tid];
#pragma unroll
    for (int j = 1; j < 16; ++j) mm = fmaxf(mm, red[tid + 16 * j]);
    mrow[tid] = mm;
  }
  __syncthreads();
  m = mrow[row];
  float s = 0.f;
  for (int i = 0; i < 32; ++i) {
    int c = seg + 16 * i;
    float e = expf(sc[row][c] - m);
    sc[row][c] = e; s += e;
  }
  red[tid] = s; __syncthreads();
  if (tid < QB) {
    float ss = red[tid];
#pragma unroll
    for (int j = 1; j < 16; ++j) ss += red[tid + 16 * j];
    invr[tid] = 1.0f / ss;
  }
  float4 o = {0.f, 0.f, 0.f, 0.f};
  int q = tid >> 4, d4 = (tid & 15) * 4;
  for (int vt = 0; vt < 4; ++vt) {
    __syncthreads();
    {
      int kk = tid >> 4, dd = (tid & 15) * 4;
#pragma unroll
      for (int i = 0; i < 8; ++i)
        *(float4*)&KVs[kk + 16 * i][dd] =
            *(const float4*)&base[(size_t)(vt * 128 + kk + 16 * i) * (3 * DM) + 2 * DM + h * HD + dd];
    }
    __syncthreads();
    for (int kk = 0; kk < 128; ++kk) {
      float w = sc[q][vt * 128 + kk];
      float4 v = *(float4*)&KVs[kk][d4];
      o.x += w * v.x; o.y += w * v.y; o.z += w * v.z; o.w += w * v.w;
    }
  }
  float iv = invr[q];
  size_t ob = (size_t)(b * SQ + q0 + q) * DM + h * HD + d4;
  float ov[4] = {o.x * iv, o.y * iv, o.z * iv, o.w * iv};
#pragma unroll
  for (int j = 0; j < 4; ++j) {
    ushort hh = f2b(ov[j]);
    aoh[ob + j] = hh;
    aol[ob + j] = f2b(ov[j] - b2f(hh));
  }
}

// ================= pipelined GEMM (r17-verified; trunc-split staging) =================
#define EPI_RES  1
#define EPI_F32  2
#define EPI_GU   3
#define EPI_DOWN 4
#define MODE_B   0
#define MODE_QKV 1
#define MODE_GU  2

template<int BM, int BN, int MODE, int EPI, int RM, int NBX, int PREC, int DEC>
__global__ __launch_bounds__(256) void k_gmm2(
    const ushort* __restrict__ Ah, const ushort* __restrict__ Al,
    const float* __restrict__ B0, const float* __restrict__ B1, const float* __restrict__ B2,
    long long bstride, ushort* __restrict__ Ch, ushort* __restrict__ Cl,
    float* __restrict__ Cf,
    int M, int K, int ldb, int ldc,
    const int* __restrict__ slot, const int* __restrict__ counts) {
  constexpr int NEg  = (RM == 0) ? 1 : NE;
  constexpr int P    = NBX * NEg;
  constexpr int Ppad = ((P + 7) / 8) * 8;
  constexpr int MB   = TT / BM;
  int id = blockIdx.x;
  int m, pp;
  if (DEC == 0) { m = id / Ppad; pp = id % Ppad; }
  else {  // DEC==2: XCD-grouped panels
    int xcd = id & 7, j = id >> 3;
    m = j % MB;
    pp = (j / MB) * 8 + xcd;
  }
  if (pp >= P) return;
  int e = pp / NBX;
  int x = pp % NBX;

  int cnt = (RM == 0) ? M : counts[e];
  int m0 = m * BM;
  if (m0 >= cnt) return;
  int n0 = x * BN;
  int off = 0;
  if (RM != 0) {
#pragma unroll
    for (int i = 0; i < NE; ++i) if (i < e) off += counts[i];
  }

  constexpr int WM = (BM == 128) ? 64 : ((BN == 128) ? 64 : 32);
  constexpr int WN = (BM == 128) ? 64 : 32;
  constexpr int MI = WM / 16, NI = WN / 16;

  __shared__ __align__(16) ushort Ahs[BM * 40];
  __shared__ __align__(16) ushort Als[(PREC == 2) ? BM * 40 : 16];
  __shared__ __align__(16) ushort Bhs[BN * 40];
  __shared__ __align__(16) ushort Bls[(PREC == 2) ? BN * 40 : 16];

  int tid = threadIdx.x;
  int wave = tid >> 6, lane = tid & 63;
  int wr, wc;
  if (BM == 128)      { wr = wave >> 1; wc = wave & 1; }
  else if (BN == 128) { wr = 0;         wc = wave;     }
  else                { wr = wave >> 1; wc = wave & 1; }
  int moff;
  if (BM == 64 && BN == 128) moff = 0; else moff = wr * ((BM == 128) ? 64 : 32);
  int noff = wc * WN;

  int arA = tid >> 2, kcA = tid & 3;
  int ar1 = tid >> 2, ar2 = ar1 + 64;
  size_t aoff1 = 0, aoff2 = 0;
  if (BM == 64) {
    int rowi;
    if (RM == 0)      rowi = m0 + arA;
    else if (RM == 1) rowi = slot[e * TT + min(m0 + arA, cnt - 1)];
    else              rowi = off + min(m0 + arA, cnt - 1);
    aoff1 = (size_t)rowi * K;
  } else {
    if (RM == 0) {
      aoff1 = (size_t)(m0 + ar1) * K;
      aoff2 = (size_t)(m0 + ar2) * K;
    } else if (RM == 1) {
      aoff1 = (size_t)slot[e * TT + min(m0 + ar1, cnt - 1)] * K;
      aoff2 = (size_t)slot[e * TT + min(m0 + ar2, cnt - 1)] * K;
    } else {
      aoff1 = (size_t)(off + min(m0 + ar1, cnt - 1)) * K;
      aoff2 = (size_t)(off + min(m0 + ar2, cnt - 1)) * K;
    }
  }

  int rB = tid & 63, ko = tid >> 6;
  auto bcol = [&](int r) -> const float* {
    if (MODE == MODE_QKV) {
      int mat = x / (NBX / 3);
      const float* Bm = (mat == 0) ? B0 : ((mat == 1) ? B1 : B2);
      return Bm + (x % (NBX / 3)) * BN + r;
    } else if (MODE == MODE_GU) {
      const float* Bg = B0 + (size_t)e * bstride;
      const float* Bu = B1 + (size_t)e * bstride;
      return ((((r) >> 4) & 1) ? Bu : Bg) + x * (BN / 2) + ((((r) >> 5) << 4) | ((r) & 15));
    }
    return B0 + (size_t)e * bstride + n0 + r;
  };
  const float* bs0 = bcol(rB);
  const float* bs1 = (BN == 128) ? bcol(rB + 64) : nullptr;

  s16x8 rah1, rah2, ral1, ral2;
  float vb0[8], vb1[8];

  auto loadA = [&](int kk) {
    if (BM == 64) {
      rah1 = *(const s16x8*)(Ah + aoff1 + kk + kcA * 8);
      if (PREC == 2) ral1 = *(const s16x8*)(Al + aoff1 + kk + kcA * 8);
    } else {
      rah1 = *(const s16x8*)(Ah + aoff1 + kk + kcA * 8);
      rah2 = *(const s16x8*)(Ah + aoff2 + kk + kcA * 8);
      if (PREC == 2) {
        ral1 = *(const s16x8*)(Al + aoff1 + kk + kcA * 8);
        ral2 = *(const s16x8*)(Al + aoff2 + kk + kcA * 8);
      }
    }
  };
  auto loadB = [&](int kk) {
#pragma unroll
    for (int i = 0; i < 8; ++i)
      vb0[i] = bs0[(size_t)(kk + ko * 8 + i) * ldb];
    if (BN == 128) {
#pragma unroll
      for (int i = 0; i < 8; ++i)
        vb1[i] = bs1[(size_t)(kk + ko * 8 + i) * ldb];
    }
  };
  auto storeLDS = [&]() {
    if (BM == 64) {
      *(s16x8*)&Ahs[arA * 40 + kcA * 8] = rah1;
      if (PREC == 2) *(s16x8*)&Als[arA * 40 + kcA * 8] = ral1;
    } else {
      *(s16x8*)&Ahs[ar1 * 40 + kcA * 8] = rah1;
      *(s16x8*)&Ahs[ar2 * 40 + kcA * 8] = rah2;
      if (PREC == 2) {
        *(s16x8*)&Als[ar1 * 40 + kcA * 8] = ral1;
        *(s16x8*)&Als[ar2 * 40 + kcA * 8] = ral2;
      }
    }
    s16x8 h0, l0;
#pragma unroll
    for (int i = 0; i < 8; ++i) {
      ushort h = t2b(vb0[i]);
      h0[i] = (short)h;
      if (PREC == 2) l0[i] = (short)t2b(vb0[i] - b2f(h));
    }
    *(s16x8*)&Bhs[rB * 40 + ko * 8] = h0;
    if (PREC == 2) *(s16x8*)&Bls[rB * 40 + ko * 8] = l0;
    if (BN == 128) {
      s16x8 h1, l1;
#pragma unroll
      for (int i = 0; i < 8; ++i) {
        ushort h = t2b(vb1[i]);
        h1[i] = (short)h;
        if (PREC == 2) l1[i] = (short)t2b(vb1[i] - b2f(h));
      }
      *(s16x8*)&Bhs[(rB + 64) * 40 + ko * 8] = h1;
      if (PREC == 2) *(s16x8*)&Bls[(rB + 64) * 40 + ko * 8] = l1;
    }
  };

  f32x4 zr = {0.f, 0.f, 0.f, 0.f};
  f32x4 acc[MI][NI];
#pragma unroll
  for (int i = 0; i < MI; ++i)
#pragma unroll
    for (int j = 0; j < NI; ++j) acc[i][j] = zr;

  int rl = lane & 15, g = lane >> 4;
  loadA(0); loadB(0);
  for (int k0 = 0; k0 < K; k0 += 32) {
    __syncthreads();
    storeLDS();
    __syncthreads();
    if (k0 + 32 < K) { loadA(k0 + 32); loadB(k0 + 32); }
#pragma unroll
    for (int mi = 0; mi < MI; ++mi) {
      int ra = (moff + mi * 16 + rl) * 40 + g * 8;
      s16x8 avh = *(const s16x8*)&Ahs[ra];
      s16x8 avl;
      if (PREC == 2) avl = *(const s16x8*)&Als[ra];
#pragma unroll
      for (int ni = 0; ni < NI; ++ni) {
        int rb = (noff + ni * 16 + rl) * 40 + g * 8;
        s16x8 bvh = *(const s16x8*)&Bhs[rb];
        f32x4 a = acc[mi][ni];
        if (PREC == 2) {
          s16x8 bvl = *(const s16x8*)&Bls[rb];
          a = __builtin_amdgcn_mfma_f32_16x16x32_bf16(avl, bvh, a, 0, 0, 0);
          a = __builtin_amdgcn_mfma_f32_16x16x32_bf16(avh, bvl, a, 0, 0, 0);
        }
        a = __builtin_amdgcn_mfma_f32_16x16x32_bf16(avh, bvh, a, 0, 0, 0);
        acc[mi][ni] = a;
      }
    }
  }

  int rg4 = (lane >> 4) * 4;
#pragma unroll
  for (int mi = 0; mi < MI; ++mi) {
#pragma unroll
    for (int rg = 0; rg < 4; ++rg) {
      int rloc = m0 + moff + mi * 16 + rg4 + rg;
      if ((EPI == EPI_GU || EPI == EPI_DOWN) && rloc >= cnt) continue;
      if (EPI == EPI_GU) {
        float gv = acc[mi][0][rg], uv = acc[mi][1][rg];
        float hv = gv / (1.f + __expf(-gv)) * uv;
        int fq = (n0 + noff) >> 5;
        size_t ix = (size_t)(off + rloc) * ldc + fq * 16 + rl;
        ushort h = t2b(hv);
        Ch[ix] = h;
        if (PREC == 2) Cl[ix] = t2b(hv - b2f(h));
      } else if (EPI == EPI_RES) {
#pragma unroll
        for (int ni = 0; ni < NI; ++ni) {
          size_t ix = (size_t)rloc * ldc + n0 + noff + ni * 16 + rl;
          Cf[ix] += acc[mi][ni][rg];
        }
      } else if (EPI == EPI_F32) {
#pragma unroll
        for (int ni = 0; ni < NI; ++ni)
          Cf[(size_t)rloc * ldc + n0 + noff + ni * 16 + rl] = acc[mi][ni][rg];
      } else {  // EPI_DOWN
#pragma unroll
        for (int ni = 0; ni < NI; ++ni)
          Cf[(size_t)(off + rloc) * ldc + n0 + noff + ni * 16 + rl] = acc[mi][ni][rg];
      }
    }
  }
}

extern "C" void kernel_launch(void* const* d_in, const int* in_sizes, int n_in,
                              void* d_out, int out_size, void* d_ws, size_t ws_size,
                              hipStream_t stream) {
  (void)in_sizes; (void)n_in; (void)out_size; (void)ws_size;
  const int*   ids = (const int*)d_in[0];
  const float* tok = (const float*)d_in[1];
  const float* pos = (const float*)d_in[2];
  const float* wq  = (const float*)d_in[3];
  const float* wk  = (const float*)d_in[4];
  const float* wv  = (const float*)d_in[5];
  const float* wo  = (const float*)d_in[6];
  const float* n1w = (const float*)d_in[7];
  const float* n2w = (const float*)d_in[8];
  const float* rw  = (const float*)d_in[9];
  const float* gw  = (const float*)d_in[10];
  const float* uw  = (const float*)d_in[11];
  const float* dw  = (const float*)d_in[12];
  const float* fnw = (const float*)d_in[13];
  const float* lmw = (const float*)d_in[14];
  float* out = (float*)d_out;

  char* p = (char*)d_ws;
  auto alloc = [&](size_t bytes) { char* r = p; p += (bytes + 255) & ~(size_t)255; return r; };
  float*  x    = (float*)alloc((size_t)TT * DM * 4);
  ushort* xh   = (ushort*)alloc((size_t)TT * DM * 2);
  ushort* xl   = (ushort*)alloc((size_t)TT * DM * 2);
  float*  qkv  = (float*)alloc((size_t)TT * 3 * DM * 4);
  ushort* aoh  = (ushort*)alloc((size_t)TT * DM * 2);
  ushort* aol  = (ushort*)alloc((size_t)TT * DM * 2);
  ushort* Hh   = (ushort*)alloc((size_t)2 * TT * FFD * 2);
  ushort* Hl   = (ushort*)alloc((size_t)2 * TT * FFD * 2);
  float*  eo   = (float*)alloc((size_t)2 * TT * DM * 4);
  float*  topw = (float*)alloc((size_t)2 * TT * 4);
  int* topi    = (int*)alloc((size_t)2 * TT * 4);
  int* posb    = (int*)alloc((size_t)2 * TT * 4);
  int* slot    = (int*)alloc((size_t)NE * TT * 4);
  int* counts4 = (int*)alloc(256);
  ushort* xnb  = (ushort*)alloc((size_t)TT * DM * 2);

  k_embed<<<TT, 256, 0, stream>>>(ids, tok, pos, x, counts4);
  k_rmsnorm_sb<<<TT, 256, 0, stream>>>(x, n1w, xh, xl);
  for (int l = 0; l < NL; ++l) {
    int* counts = counts4 + NE * l;
    // attention
    k_gmm2<64, 64, MODE_QKV, EPI_F32, 0, 36, 2, 0><<<16 * 40, 256, 0, stream>>>(
        xh, xl, wq + (size_t)l * DM * DM, wk + (size_t)l * DM * DM, wv + (size_t)l * DM * DM,
        0, nullptr, nullptr, qkv, TT, DM, DM, 3 * DM, nullptr, nullptr);
    k_attn2<<<dim3(SQ / QB, NH, NB), 256, 0, stream>>>(qkv, aoh, aol);
    k_gmm2<64, 64, MODE_B, EPI_RES, 0, 12, 2, 0><<<16 * 16, 256, 0, stream>>>(
        aoh, aol, wo + (size_t)l * DM * DM, nullptr, nullptr,
        0, nullptr, nullptr, x, TT, DM, DM, DM, nullptr, nullptr);

    // MoE: fused norm+router, then expert GEMMs
    k_rmsnorm_rt<<<TT, 256, 0, stream>>>(x, n2w + l * DM, rw + (size_t)l * DM * NE,
                                         xh, xl, topi, topw, posb, slot, counts);
    if (l < NL - 1) {
      k_gmm2<64, 128, MODE_GU, EPI_GU, 1, 32, 2, 0><<<16 * 256, 256, 0, stream>>>(
          xh, xl, gw + (size_t)l * NE * DM * FFD, uw + (size_t)l * NE * DM * FFD, nullptr,
          (long long)DM * FFD, Hh, Hl, nullptr, TT, DM, FFD, FFD, slot, counts);
      k_gmm2<64, 64, MODE_B, EPI_DOWN, 2, 12, 2, 0><<<16 * 96, 256, 0, stream>>>(
          Hh, Hl, dw + (size_t)l * NE * FFD * DM, nullptr, nullptr,
          (long long)FFD * DM, nullptr, nullptr, eo, TT, FFD, DM, DM, nullptr, counts);
      k_combine_norm<0><<<TT, 256, 0, stream>>>(eo, topi, topw, posb, counts,
                                                x, n1w + (size_t)(l + 1) * DM, xh, xl);
    } else {
      k_gmm2<64, 128, MODE_GU, EPI_GU, 1, 32, 1, 0><<<16 * 256, 256, 0, stream>>>(
          xh, nullptr, gw + (size_t)l * NE * DM * FFD, uw + (size_t)l * NE * DM * FFD, nullptr,
          (long long)DM * FFD, Hh, nullptr, nullptr, TT, DM, FFD, FFD, slot, counts);
      k_gmm2<64, 64, MODE_B, EPI_DOWN, 2, 12, 1, 0><<<16 * 96, 256, 0, stream>>>(
          Hh, nullptr, dw + (size_t)l * NE * FFD * DM, nullptr, nullptr,
          (long long)FFD * DM, nullptr, nullptr, eo, TT, FFD, DM, DM, nullptr, counts);
      k_combine_norm<1><<<TT, 256, 0, stream>>>(eo, topi, topw, posb, counts,
                                                x, fnw, xnb, nullptr);
    }
  }

  // LM head: single launch, XCD-grouped panel decode
  k_gmm2<64, 128, MODE_B, EPI_F32, 0, 250, 1, 2><<<16 * 256, 256, 0, stream>>>(
      xnb, nullptr, lmw, nullptr, nullptr,
      0, nullptr, nullptr, out, TT, DM, NV, NV, nullptr, nullptr);
}

// Round 22
// 1337.705 us; speedup vs baseline: 1.0530x; 1.0005x over previous
//
#include <hip/hip_runtime.h>
#include <math.h>

#define TT   1024
#define DM   768
#define NH   12
#define HD   64
#define FFD  2048
#define NE   8
#define SQ   512
#define NB   2
#define NL   4
#define NV   32000
#define REPS 1e-6f
#define QB   16

typedef float f32x4 __attribute__((ext_vector_type(4)));
typedef short s16x8 __attribute__((ext_vector_type(8)));

__device__ __forceinline__ float b2f(ushort u) {
  return __uint_as_float(((unsigned)u) << 16);
}
__device__ __forceinline__ ushort f2b(float f) {
  unsigned i = __float_as_uint(f);
  return (ushort)((i + 0x7FFFu + ((i >> 16) & 1u)) >> 16);
}
__device__ __forceinline__ ushort t2b(float f) {  // truncate: 1 VALU op
  return (ushort)(__float_as_uint(f) >> 16);
}

// ================= embed (+ zero all per-layer counts) =================
__global__ __launch_bounds__(256) void k_embed(const int* __restrict__ ids,
    const float* __restrict__ tok, const float* __restrict__ pos, float* __restrict__ x,
    int* __restrict__ counts4) {
  int t = blockIdx.x;
  if (t == 0 && threadIdx.x < NL * NE) counts4[threadIdx.x] = 0;
  int s = t % SQ; int id = ids[t];
  for (int d = threadIdx.x; d < DM; d += 256)
    x[t * DM + d] = tok[(size_t)id * DM + d] + pos[s * DM + d];
}

// ================= first-layer rmsnorm -> split =================
__global__ __launch_bounds__(256) void k_rmsnorm_sb(const float* __restrict__ x,
    const float* __restrict__ w, ushort* __restrict__ yh, ushort* __restrict__ yl) {
  __shared__ float red[256];
  int t = blockIdx.x, tid = threadIdx.x;
  float ss = 0.f;
  for (int d = tid; d < DM; d += 256) { float v = x[t * DM + d]; ss += v * v; }
  red[tid] = ss; __syncthreads();
  for (int s = 128; s > 0; s >>= 1) { if (tid < s) red[tid] += red[tid + s]; __syncthreads(); }
  float inv = 1.0f / sqrtf(red[0] / (float)DM + REPS);
  for (int d = tid; d < DM; d += 256) {
    float v = w[d] * x[t * DM + d] * inv;
    ushort h = f2b(v);
    yh[t * DM + d] = h;
    yl[t * DM + d] = f2b(v - b2f(h));
  }
}

// ================= fused MoE rmsnorm + router =================
__global__ __launch_bounds__(256) void k_rmsnorm_rt(const float* __restrict__ x,
    const float* __restrict__ nw, const float* __restrict__ rw,
    ushort* __restrict__ yh, ushort* __restrict__ yl,
    int* __restrict__ topi, float* __restrict__ topw,
    int* __restrict__ posb, int* __restrict__ slot, int* __restrict__ counts) {
  __shared__ float red[256];
  __shared__ float rw4[4][NE];
  int t = blockIdx.x, tid = threadIdx.x;
  float xs[3];
  float ss = 0.f;
#pragma unroll
  for (int i = 0; i < 3; ++i) {
    float v = x[t * DM + tid + 256 * i];
    xs[i] = v; ss += v * v;
  }
  red[tid] = ss; __syncthreads();
  for (int s = 128; s > 0; s >>= 1) { if (tid < s) red[tid] += red[tid + s]; __syncthreads(); }
  float inv = 1.0f / sqrtf(red[0] / (float)DM + REPS);
  float acc[NE] = {};
#pragma unroll
  for (int i = 0; i < 3; ++i) {
    int d = tid + 256 * i;
    float v = nw[d] * xs[i] * inv;
    ushort h = f2b(v);
    yh[t * DM + d] = h;
    yl[t * DM + d] = f2b(v - b2f(h));
    const float* r = &rw[d * NE];
#pragma unroll
    for (int e = 0; e < NE; ++e) acc[e] += v * r[e];
  }
#pragma unroll
  for (int off = 32; off > 0; off >>= 1)
#pragma unroll
    for (int e = 0; e < NE; ++e) acc[e] += __shfl_down(acc[e], off, 64);
  int wv = tid >> 6, ln = tid & 63;
  if (ln == 0)
#pragma unroll
    for (int e = 0; e < NE; ++e) rw4[wv][e] = acc[e];
  __syncthreads();
  if (tid == 0) {
    float lg[NE];
#pragma unroll
    for (int e = 0; e < NE; ++e) lg[e] = rw4[0][e] + rw4[1][e] + rw4[2][e] + rw4[3][e];
    int i0 = 0;
    for (int e = 1; e < NE; ++e) if (lg[e] > lg[i0]) i0 = e;
    int i1 = (i0 == 0) ? 1 : 0;
    for (int e = 0; e < NE; ++e) if (e != i0 && lg[e] > lg[i1]) i1 = e;
    float e1 = __expf(lg[i1] - lg[i0]);
    float w0 = 1.f / (1.f + e1), w1 = e1 / (1.f + e1);
    int p0 = atomicAdd(&counts[i0], 1);
    int p1 = atomicAdd(&counts[i1], 1);
    topi[2 * t] = i0; topi[2 * t + 1] = i1;
    topw[2 * t] = w0; topw[2 * t + 1] = w1;
    posb[2 * t] = p0; posb[2 * t + 1] = p1;
    slot[i0 * TT + p0] = t; slot[i1 * TT + p1] = t;
  }
}

// ================= fused combine + next norm =================
template<int FINAL>
__global__ __launch_bounds__(256) void k_combine_norm(const float* __restrict__ eo,
    const int* __restrict__ topi, const float* __restrict__ topw,
    const int* __restrict__ posb, const int* __restrict__ counts,
    float* __restrict__ x, const float* __restrict__ w,
    ushort* __restrict__ yh, ushort* __restrict__ yl) {
  __shared__ float red[256];
  int t = blockIdx.x, tid = threadIdx.x;
  int pre[NE]; int a = 0;
#pragma unroll
  for (int e = 0; e < NE; ++e) { pre[e] = a; a += counts[e]; }
  int r0 = pre[topi[2 * t]] + posb[2 * t];
  int r1 = pre[topi[2 * t + 1]] + posb[2 * t + 1];
  float w0 = topw[2 * t], w1 = topw[2 * t + 1];
  float nv[3];
  float ss = 0.f;
#pragma unroll
  for (int i = 0; i < 3; ++i) {
    int d = tid + 256 * i;
    float v = x[t * DM + d] + w0 * eo[(size_t)r0 * DM + d] + w1 * eo[(size_t)r1 * DM + d];
    x[t * DM + d] = v;
    nv[i] = v; ss += v * v;
  }
  red[tid] = ss; __syncthreads();
  for (int s = 128; s > 0; s >>= 1) { if (tid < s) red[tid] += red[tid + s]; __syncthreads(); }
  float inv = 1.0f / sqrtf(red[0] / (float)DM + REPS);
#pragma unroll
  for (int i = 0; i < 3; ++i) {
    int d = tid + 256 * i;
    float u = w[d] * nv[i] * inv;
    if (FINAL) {
      yh[t * DM + d] = f2b(u);
    } else {
      ushort h = f2b(u);
      yh[t * DM + d] = h;
      yl[t * DM + d] = f2b(u - b2f(h));
    }
  }
}

// ================= tiled fp32 attention, split-output epilogue (r15-verified) =================
__global__ __launch_bounds__(256) void k_attn2(const float* __restrict__ qkv,
    ushort* __restrict__ aoh, ushort* __restrict__ aol) {
  __shared__ float Qs[QB][64];
  __shared__ float KVs[128][68];
  __shared__ float sc[QB][516];
  __shared__ float red[256];
  __shared__ float mrow[QB], invr[QB];
  int qt = blockIdx.x, h = blockIdx.y, b = blockIdx.z;
  int tid = threadIdx.x;
  int q0 = qt * QB;
  const float* base = qkv + (size_t)(b * SQ) * (3 * DM);
  {
    int qi = tid >> 4, d4 = (tid & 15) * 4;
    *(float4*)&Qs[qi][d4] = *(const float4*)&base[(size_t)(q0 + qi) * (3 * DM) + h * HD + d4];
  }
  for (int kt = 0; kt < 4; ++kt) {
    __syncthreads();
    {
      int kk = tid >> 4, d4 = (tid & 15) * 4;
#pragma unroll
      for (int i = 0; i < 8; ++i)
        *(float4*)&KVs[kk + 16 * i][d4] =
            *(const float4*)&base[(size_t)(kt * 128 + kk + 16 * i) * (3 * DM) + DM + h * HD + d4];
    }
    __syncthreads();
    int q2 = tid >> 5, k4 = tid & 31;
    float a0[4] = {}, a1[4] = {};
#pragma unroll
    for (int i = 0; i < 16; ++i) {
      float4 qa = *(float4*)&Qs[2 * q2][4 * i];
      float4 qb = *(float4*)&Qs[2 * q2 + 1][4 * i];
#pragma unroll
      for (int j = 0; j < 4; ++j) {
        float4 kv = *(float4*)&KVs[k4 + 32 * j][4 * i];
        a0[j] += qa.x * kv.x + qa.y * kv.y + qa.z * kv.z + qa.w * kv.w;
        a1[j] += qb.x * kv.x + qb.y * kv.y + qb.z * kv.z + qb.w * kv.w;
      }
    }
#pragma unroll
    for (int j = 0; j < 4; ++j) {
      sc[2 * q2][kt * 128 + 32 * j + k4] = a0[j] * 0.125f;
      sc[2 * q2 + 1][kt * 128 + 32 * j + k4] = a1[j] * 0.125f;
    }
  }
  __syncthreads();
  int row = tid & 15, seg = tid >> 4;
  float m = -1e30f;
  for (int i = 0; i < 32; ++i) m = fmaxf(m, sc[row][seg + 16 * i]);
  red[tid] = m; __syncthreads();
  if (tid < QB) {
    float mm = red[tid];
#pragma unroll
    for (int j = 1; j < 16; ++j) mm = fmaxf(mm, red[tid + 16 * j]);
    mrow[tid] = mm;
  }
  __syncthreads();
  m = mrow[row];
  float s = 0.f;
  for (int i = 0; i < 32; ++i) {
    int c = seg + 16 * i;
    float e = expf(sc[row][c] - m);
    sc[row][c] = e; s += e;
  }
  red[tid] = s; __syncthreads();
  if (tid < QB) {
    float ss = red[tid];
#pragma unroll
    for (int j = 1; j < 16; ++j) ss += red[tid + 16 * j];
    invr[tid] = 1.0f / ss;
  }
  float4 o = {0.f, 0.f, 0.f, 0.f};
  int q = tid >> 4, d4 = (tid & 15) * 4;
  for (int vt = 0; vt < 4; ++vt) {
    __syncthreads();
    {
      int kk = tid >> 4, dd = (tid & 15) * 4;
#pragma unroll
      for (int i = 0; i < 8; ++i)
        *(float4*)&KVs[kk + 16 * i][dd] =
            *(const float4*)&base[(size_t)(vt * 128 + kk + 16 * i) * (3 * DM) + 2 * DM + h * HD + dd];
    }
    __syncthreads();
    for (int kk = 0; kk < 128; ++kk) {
      float w = sc[q][vt * 128 + kk];
      float4 v = *(float4*)&KVs[kk][d4];
      o.x += w * v.x; o.y += w * v.y; o.z += w * v.z; o.w += w * v.w;
    }
  }
  float iv = invr[q];
  size_t ob = (size_t)(b * SQ + q0 + q) * DM + h * HD + d4;
  float ov[4] = {o.x * iv, o.y * iv, o.z * iv, o.w * iv};
#pragma unroll
  for (int j = 0; j < 4; ++j) {
    ushort hh = f2b(ov[j]);
    aoh[ob + j] = hh;
    aol[ob + j] = f2b(ov[j] - b2f(hh));
  }
}

// ================= pipelined GEMM (r17-verified; trunc-split staging) =================
#define EPI_RES  1
#define EPI_F32  2
#define EPI_GU   3
#define EPI_DOWN 4
#define MODE_B   0
#define MODE_QKV 1
#define MODE_GU  2

template<int BM, int BN, int MODE, int EPI, int RM, int NBX, int PREC, int DEC>
__global__ __launch_bounds__(256) void k_gmm2(
    const ushort* __restrict__ Ah, const ushort* __restrict__ Al,
    const float* __restrict__ B0, const float* __restrict__ B1, const float* __restrict__ B2,
    long long bstride, ushort* __restrict__ Ch, ushort* __restrict__ Cl,
    float* __restrict__ Cf,
    int M, int K, int ldb, int ldc,
    const int* __restrict__ slot, const int* __restrict__ counts) {
  constexpr int NEg  = (RM == 0) ? 1 : NE;
  constexpr int P    = NBX * NEg;
  constexpr int Ppad = ((P + 7) / 8) * 8;
  constexpr int MB   = TT / BM;
  int id = blockIdx.x;
  int m, pp;
  if (DEC == 0) { m = id / Ppad; pp = id % Ppad; }
  else {  // DEC==2: XCD-grouped panels
    int xcd = id & 7, j = id >> 3;
    m = j % MB;
    pp = (j / MB) * 8 + xcd;
  }
  if (pp >= P) return;
  int e = pp / NBX;
  int x = pp % NBX;

  int cnt = (RM == 0) ? M : counts[e];
  int m0 = m * BM;
  if (m0 >= cnt) return;
  int n0 = x * BN;
  int off = 0;
  if (RM != 0) {
#pragma unroll
    for (int i = 0; i < NE; ++i) if (i < e) off += counts[i];
  }

  constexpr int WM = (BM == 128) ? 64 : ((BN == 128) ? 64 : 32);
  constexpr int WN = (BM == 128) ? 64 : 32;
  constexpr int MI = WM / 16, NI = WN / 16;

  __shared__ __align__(16) ushort Ahs[BM * 40];
  __shared__ __align__(16) ushort Als[(PREC == 2) ? BM * 40 : 16];
  __shared__ __align__(16) ushort Bhs[BN * 40];
  __shared__ __align__(16) ushort Bls[(PREC == 2) ? BN * 40 : 16];

  int tid = threadIdx.x;
  int wave = tid >> 6, lane = tid & 63;
  int wr, wc;
  if (BM == 128)      { wr = wave >> 1; wc = wave & 1; }
  else if (BN == 128) { wr = 0;         wc = wave;     }
  else                { wr = wave >> 1; wc = wave & 1; }
  int moff;
  if (BM == 64 && BN == 128) moff = 0; else moff = wr * ((BM == 128) ? 64 : 32);
  int noff = wc * WN;

  int arA = tid >> 2, kcA = tid & 3;
  int ar1 = tid >> 2, ar2 = ar1 + 64;
  size_t aoff1 = 0, aoff2 = 0;
  if (BM == 64) {
    int rowi;
    if (RM == 0)      rowi = m0 + arA;
    else if (RM == 1) rowi = slot[e * TT + min(m0 + arA, cnt - 1)];
    else              rowi = off + min(m0 + arA, cnt - 1);
    aoff1 = (size_t)rowi * K;
  } else {
    if (RM == 0) {
      aoff1 = (size_t)(m0 + ar1) * K;
      aoff2 = (size_t)(m0 + ar2) * K;
    } else if (RM == 1) {
      aoff1 = (size_t)slot[e * TT + min(m0 + ar1, cnt - 1)] * K;
      aoff2 = (size_t)slot[e * TT + min(m0 + ar2, cnt - 1)] * K;
    } else {
      aoff1 = (size_t)(off + min(m0 + ar1, cnt - 1)) * K;
      aoff2 = (size_t)(off + min(m0 + ar2, cnt - 1)) * K;
    }
  }

  int rB = tid & 63, ko = tid >> 6;
  auto bcol = [&](int r) -> const float* {
    if (MODE == MODE_QKV) {
      int mat = x / (NBX / 3);
      const float* Bm = (mat == 0) ? B0 : ((mat == 1) ? B1 : B2);
      return Bm + (x % (NBX / 3)) * BN + r;
    } else if (MODE == MODE_GU) {
      const float* Bg = B0 + (size_t)e * bstride;
      const float* Bu = B1 + (size_t)e * bstride;
      return ((((r) >> 4) & 1) ? Bu : Bg) + x * (BN / 2) + ((((r) >> 5) << 4) | ((r) & 15));
    }
    return B0 + (size_t)e * bstride + n0 + r;
  };
  const float* bs0 = bcol(rB);
  const float* bs1 = (BN == 128) ? bcol(rB + 64) : nullptr;

  s16x8 rah1, rah2, ral1, ral2;
  float vb0[8], vb1[8];

  auto loadA = [&](int kk) {
    if (BM == 64) {
      rah1 = *(const s16x8*)(Ah + aoff1 + kk + kcA * 8);
      if (PREC == 2) ral1 = *(const s16x8*)(Al + aoff1 + kk + kcA * 8);
    } else {
      rah1 = *(const s16x8*)(Ah + aoff1 + kk + kcA * 8);
      rah2 = *(const s16x8*)(Ah + aoff2 + kk + kcA * 8);
      if (PREC == 2) {
        ral1 = *(const s16x8*)(Al + aoff1 + kk + kcA * 8);
        ral2 = *(const s16x8*)(Al + aoff2 + kk + kcA * 8);
      }
    }
  };
  auto loadB = [&](int kk) {
#pragma unroll
    for (int i = 0; i < 8; ++i)
      vb0[i] = bs0[(size_t)(kk + ko * 8 + i) * ldb];
    if (BN == 128) {
#pragma unroll
      for (int i = 0; i < 8; ++i)
        vb1[i] = bs1[(size_t)(kk + ko * 8 + i) * ldb];
    }
  };
  auto storeLDS = [&]() {
    if (BM == 64) {
      *(s16x8*)&Ahs[arA * 40 + kcA * 8] = rah1;
      if (PREC == 2) *(s16x8*)&Als[arA * 40 + kcA * 8] = ral1;
    } else {
      *(s16x8*)&Ahs[ar1 * 40 + kcA * 8] = rah1;
      *(s16x8*)&Ahs[ar2 * 40 + kcA * 8] = rah2;
      if (PREC == 2) {
        *(s16x8*)&Als[ar1 * 40 + kcA * 8] = ral1;
        *(s16x8*)&Als[ar2 * 40 + kcA * 8] = ral2;
      }
    }
    s16x8 h0, l0;
#pragma unroll
    for (int i = 0; i < 8; ++i) {
      ushort h = t2b(vb0[i]);
      h0[i] = (short)h;
      if (PREC == 2) l0[i] = (short)t2b(vb0[i] - b2f(h));
    }
    *(s16x8*)&Bhs[rB * 40 + ko * 8] = h0;
    if (PREC == 2) *(s16x8*)&Bls[rB * 40 + ko * 8] = l0;
    if (BN == 128) {
      s16x8 h1, l1;
#pragma unroll
      for (int i = 0; i < 8; ++i) {
        ushort h = t2b(vb1[i]);
        h1[i] = (short)h;
        if (PREC == 2) l1[i] = (short)t2b(vb1[i] - b2f(h));
      }
      *(s16x8*)&Bhs[(rB + 64) * 40 + ko * 8] = h1;
      if (PREC == 2) *(s16x8*)&Bls[(rB + 64) * 40 + ko * 8] = l1;
    }
  };

  f32x4 zr = {0.f, 0.f, 0.f, 0.f};
  f32x4 acc[MI][NI];
#pragma unroll
  for (int i = 0; i < MI; ++i)
#pragma unroll
    for (int j = 0; j < NI; ++j) acc[i][j] = zr;

  int rl = lane & 15, g = lane >> 4;
  loadA(0); loadB(0);
  for (int k0 = 0; k0 < K; k0 += 32) {
    __syncthreads();
    storeLDS();
    __syncthreads();
    if (k0 + 32 < K) { loadA(k0 + 32); loadB(k0 + 32); }
#pragma unroll
    for (int mi = 0; mi < MI; ++mi) {
      int ra = (moff + mi * 16 + rl) * 40 + g * 8;
      s16x8 avh = *(const s16x8*)&Ahs[ra];
      s16x8 avl;
      if (PREC == 2) avl = *(const s16x8*)&Als[ra];
#pragma unroll
      for (int ni = 0; ni < NI; ++ni) {
        int rb = (noff + ni * 16 + rl) * 40 + g * 8;
        s16x8 bvh = *(const s16x8*)&Bhs[rb];
        f32x4 a = acc[mi][ni];
        if (PREC == 2) {
          s16x8 bvl = *(const s16x8*)&Bls[rb];
          a = __builtin_amdgcn_mfma_f32_16x16x32_bf16(avl, bvh, a, 0, 0, 0);
          a = __builtin_amdgcn_mfma_f32_16x16x32_bf16(avh, bvl, a, 0, 0, 0);
        }
        a = __builtin_amdgcn_mfma_f32_16x16x32_bf16(avh, bvh, a, 0, 0, 0);
        acc[mi][ni] = a;
      }
    }
  }

  int rg4 = (lane >> 4) * 4;
#pragma unroll
  for (int mi = 0; mi < MI; ++mi) {
#pragma unroll
    for (int rg = 0; rg < 4; ++rg) {
      int rloc = m0 + moff + mi * 16 + rg4 + rg;
      if ((EPI == EPI_GU || EPI == EPI_DOWN) && rloc >= cnt) continue;
      if (EPI == EPI_GU) {
        float gv = acc[mi][0][rg], uv = acc[mi][1][rg];
        float hv = gv / (1.f + __expf(-gv)) * uv;
        int fq = (n0 + noff) >> 5;
        size_t ix = (size_t)(off + rloc) * ldc + fq * 16 + rl;
        ushort h = t2b(hv);
        Ch[ix] = h;
        if (PREC == 2) Cl[ix] = t2b(hv - b2f(h));
      } else if (EPI == EPI_RES) {
#pragma unroll
        for (int ni = 0; ni < NI; ++ni) {
          size_t ix = (size_t)rloc * ldc + n0 + noff + ni * 16 + rl;
          Cf[ix] += acc[mi][ni][rg];
        }
      } else if (EPI == EPI_F32) {
#pragma unroll
        for (int ni = 0; ni < NI; ++ni)
          Cf[(size_t)rloc * ldc + n0 + noff + ni * 16 + rl] = acc[mi][ni][rg];
      } else {  // EPI_DOWN
#pragma unroll
        for (int ni = 0; ni < NI; ++ni)
          Cf[(size_t)(off + rloc) * ldc + n0 + noff + ni * 16 + rl] = acc[mi][ni][rg];
      }
    }
  }
}

extern "C" void kernel_launch(void* const* d_in, const int* in_sizes, int n_in,
                              void* d_out, int out_size, void* d_ws, size_t ws_size,
                              hipStream_t stream) {
  (void)in_sizes; (void)n_in; (void)out_size; (void)ws_size;
  const int*   ids = (const int*)d_in[0];
  const float* tok = (const float*)d_in[1];
  const float* pos = (const float*)d_in[2];
  const float* wq  = (const float*)d_in[3];
  const float* wk  = (const float*)d_in[4];
  const float* wv  = (const float*)d_in[5];
  const float* wo  = (const float*)d_in[6];
  const float* n1w = (const float*)d_in[7];
  const float* n2w = (const float*)d_in[8];
  const float* rw  = (const float*)d_in[9];
  const float* gw  = (const float*)d_in[10];
  const float* uw  = (const float*)d_in[11];
  const float* dw  = (const float*)d_in[12];
  const float* fnw = (const float*)d_in[13];
  const float* lmw = (const float*)d_in[14];
  float* out = (float*)d_out;

  char* p = (char*)d_ws;
  auto alloc = [&](size_t bytes) { char* r = p; p += (bytes + 255) & ~(size_t)255; return r; };
  float*  x    = (float*)alloc((size_t)TT * DM * 4);
  ushort* xh   = (ushort*)alloc((size_t)TT * DM * 2);
  ushort* xl   = (ushort*)alloc((size_t)TT * DM * 2);
  float*  qkv  = (float*)alloc((size_t)TT * 3 * DM * 4);
  ushort* aoh  = (ushort*)alloc((size_t)TT * DM * 2);
  ushort* aol  = (ushort*)alloc((size_t)TT * DM * 2);
  ushort* Hh   = (ushort*)alloc((size_t)2 * TT * FFD * 2);
  ushort* Hl   = (ushort*)alloc((size_t)2 * TT * FFD * 2);
  float*  eo   = (float*)alloc((size_t)2 * TT * DM * 4);
  float*  topw = (float*)alloc((size_t)2 * TT * 4);
  int* topi    = (int*)alloc((size_t)2 * TT * 4);
  int* posb    = (int*)alloc((size_t)2 * TT * 4);
  int* slot    = (int*)alloc((size_t)NE * TT * 4);
  int* counts4 = (int*)alloc(256);
  ushort* xnb  = (ushort*)alloc((size_t)TT * DM * 2);

  k_embed<<<TT, 256, 0, stream>>>(ids, tok, pos, x, counts4);
  k_rmsnorm_sb<<<TT, 256, 0, stream>>>(x, n1w, xh, xl);
  for (int l = 0; l < NL; ++l) {
    int* counts = counts4 + NE * l;
    // attention
    k_gmm2<64, 64, MODE_QKV, EPI_F32, 0, 36, 2, 0><<<16 * 40, 256, 0, stream>>>(
        xh, xl, wq + (size_t)l * DM * DM, wk + (size_t)l * DM * DM, wv + (size_t)l * DM * DM,
        0, nullptr, nullptr, qkv, TT, DM, DM, 3 * DM, nullptr, nullptr);
    k_attn2<<<dim3(SQ / QB, NH, NB), 256, 0, stream>>>(qkv, aoh, aol);
    k_gmm2<64, 64, MODE_B, EPI_RES, 0, 12, 2, 0><<<16 * 16, 256, 0, stream>>>(
        aoh, aol, wo + (size_t)l * DM * DM, nullptr, nullptr,
        0, nullptr, nullptr, x, TT, DM, DM, DM, nullptr, nullptr);

    // MoE: fused norm+router, then expert GEMMs
    k_rmsnorm_rt<<<TT, 256, 0, stream>>>(x, n2w + l * DM, rw + (size_t)l * DM * NE,
                                         xh, xl, topi, topw, posb, slot, counts);
    if (l < NL - 1) {
      k_gmm2<64, 128, MODE_GU, EPI_GU, 1, 32, 2, 0><<<16 * 256, 256, 0, stream>>>(
          xh, xl, gw + (size_t)l * NE * DM * FFD, uw + (size_t)l * NE * DM * FFD, nullptr,
          (long long)DM * FFD, Hh, Hl, nullptr, TT, DM, FFD, FFD, slot, counts);
      k_gmm2<64, 64, MODE_B, EPI_DOWN, 2, 12, 2, 0><<<16 * 96, 256, 0, stream>>>(
          Hh, Hl, dw + (size_t)l * NE * FFD * DM, nullptr, nullptr,
          (long long)FFD * DM, nullptr, nullptr, eo, TT, FFD, DM, DM, nullptr, counts);
      k_combine_norm<0><<<TT, 256, 0, stream>>>(eo, topi, topw, posb, counts,
                                                x, n1w + (size_t)(l + 1) * DM, xh, xl);
    } else {
      k_gmm2<64, 128, MODE_GU, EPI_GU, 1, 32, 1, 0><<<16 * 256, 256, 0, stream>>>(
          xh, nullptr, gw + (size_t)l * NE * DM * FFD, uw + (size_t)l * NE * DM * FFD, nullptr,
          (long long)DM * FFD, Hh, nullptr, nullptr, TT, DM, FFD, FFD, slot, counts);
      k_gmm2<64, 64, MODE_B, EPI_DOWN, 2, 12, 1, 0><<<16 * 96, 256, 0, stream>>>(
          Hh, nullptr, dw + (size_t)l * NE * FFD * DM, nullptr, nullptr,
          (long long)FFD * DM, nullptr, nullptr, eo, TT, FFD, DM, DM, nullptr, counts);
      k_combine_norm<1><<<TT, 256, 0, stream>>>(eo, topi, topw, posb, counts,
                                                x, fnw, xnb, nullptr);
    }
  }

  // LM head: single launch, XCD-grouped panel decode
  k_gmm2<64, 128, MODE_B, EPI_F32, 0, 250, 1, 2><<<16 * 256, 256, 0, stream>>>(
      xnb, nullptr, lmw, nullptr, nullptr,
      0, nullptr, nullptr, out, TT, DM, NV, NV, nullptr, nullptr);
}